// Round 1
// baseline (356.838 us; speedup 1.0000x reference)
//
#include <hip/hip_runtime.h>
#include <hip/hip_bf16.h>
#include <stdint.h>

// ---------- types ----------
using frag8 = __attribute__((ext_vector_type(8))) short;   // 8 bf16 (4 VGPRs)
using f32x4 = __attribute__((ext_vector_type(4))) float;   // 4 fp32 acc

#define MFMA16 __builtin_amdgcn_mfma_f32_16x16x32_bf16

__device__ __forceinline__ short f2bf(float f) {
    union { float f; uint32_t u; } x; x.f = f;
    uint32_t r = x.u + 0x7fffu + ((x.u >> 16) & 1u);
    return (short)(r >> 16);
}
__device__ __forceinline__ float bf2f(short s) {
    union { uint32_t u; float f; } x; x.u = ((uint32_t)(uint16_t)s) << 16;
    return x.f;
}

// ---------- K0: fp32 -> bf16 convert ----------
__global__ __launch_bounds__(256) void k_cvt(const float* __restrict__ src,
                                             short* __restrict__ dst, int n4) {
    int i = blockIdx.x * blockDim.x + threadIdx.x;
    int st = gridDim.x * blockDim.x;
    for (; i < n4; i += st) {
        float4 v = reinterpret_cast<const float4*>(src)[i];
        ushort4 o;
        o.x = (uint16_t)f2bf(v.x);
        o.y = (uint16_t)f2bf(v.y);
        o.z = (uint16_t)f2bf(v.z);
        o.w = (uint16_t)f2bf(v.w);
        reinterpret_cast<ushort4*>(dst)[i] = o;
    }
}

// ---------- GEMM core helpers (128x128 tile, BK=32, 4 waves 2x2) ----------
__device__ __forceinline__ void stage_tiles(const short* __restrict__ As,
                                            const short* __restrict__ Bs,
                                            short* lA, short* lB,
                                            int w, int ln) {
    // A/B tiles: 128 rows x 32 cols bf16 = 8KB each. 512 chunks of 16B per tile.
    // wave w, call j covers chunks [(w*2+j)*64 .. +64)
#pragma unroll
    for (int j = 0; j < 2; j++) {
        int cb = (w * 2 + j) * 64;
        int c  = cb + ln;
        int row = c >> 2, c8 = c & 3;
        __builtin_amdgcn_global_load_lds(
            (const __attribute__((address_space(1))) uint32_t*)(As + row * 1024 + c8 * 8),
            (__attribute__((address_space(3))) uint32_t*)(lA + cb * 8), 16, 0, 0);
        __builtin_amdgcn_global_load_lds(
            (const __attribute__((address_space(1))) uint32_t*)(Bs + row * 1024 + c8 * 8),
            (__attribute__((address_space(3))) uint32_t*)(lB + cb * 8), 16, 0, 0);
    }
}

// ---------- K1: projection GEMM: dst[b,h,seq,64] = bf16(A @ Wt + bias) ----------
__global__ __launch_bounds__(256) void k_proj(const short* __restrict__ A,   // [4096][1024] bf16
                                              const short* __restrict__ Bt,  // [1024][1024] bf16 (row = out feature)
                                              const float* __restrict__ bias,
                                              short* __restrict__ dst) {     // [32][2048][64] bf16
    __shared__ short lA[2][4096];
    __shared__ short lB[2][4096];
    const int tid = threadIdx.x, w = tid >> 6, ln = tid & 63;
    const int wm = w >> 1, wn = w & 1, r16 = ln & 15, g = ln >> 4;
    const int tn = blockIdx.x * 128, tm = blockIdx.y * 128;
    const short* Ab = A + (size_t)tm * 1024;
    const short* Bb = Bt + (size_t)tn * 1024;

    f32x4 acc[4][4] = {};
    stage_tiles(Ab, Bb, &lA[0][0], &lB[0][0], w, ln);
    int buf = 0;
    for (int ks = 0; ks < 32; ks++) {
        __syncthreads();  // drains vmcnt: staged tile ready; prev reads done
        if (ks + 1 < 32)
            stage_tiles(Ab + (ks + 1) * 32, Bb + (ks + 1) * 32,
                        &lA[buf ^ 1][0], &lB[buf ^ 1][0], w, ln);
        frag8 af[4], bg[4];
#pragma unroll
        for (int mf = 0; mf < 4; mf++)
            af[mf] = *(const frag8*)&lA[buf][(wm * 64 + mf * 16 + r16) * 32 + g * 8];
#pragma unroll
        for (int nf = 0; nf < 4; nf++)
            bg[nf] = *(const frag8*)&lB[buf][(wn * 64 + nf * 16 + r16) * 32 + g * 8];
#pragma unroll
        for (int mf = 0; mf < 4; mf++)
#pragma unroll
            for (int nf = 0; nf < 4; nf++)
                acc[mf][nf] = MFMA16(af[mf], bg[nf], acc[mf][nf], 0, 0, 0);
        buf ^= 1;
    }
    // epilogue: scatter to [b*16+h][seq][d]
#pragma unroll
    for (int mf = 0; mf < 4; mf++)
#pragma unroll
        for (int nf = 0; nf < 4; nf++)
#pragma unroll
            for (int r = 0; r < 4; r++) {
                int m = tm + wm * 64 + mf * 16 + g * 4 + r;
                int n = tn + wn * 64 + nf * 16 + r16;
                float val = acc[mf][nf][r] + bias[n];
                int b = m >> 11, seq = m & 2047, h = n >> 6, d = n & 63;
                dst[((size_t)(b * 16 + h) * 2048 + seq) * 64 + d] = f2bf(val);
            }
}

// ---------- K2: column stats D[bh][k] = sum_q(masked) exp(S[q,k]) ----------
__global__ __launch_bounds__(256) void k_stats(const short* __restrict__ k_s,  // [32][2048][64]
                                               const short* __restrict__ q_s,  // [32][2048][64]
                                               const int* __restrict__ mask,   // [2][2048]
                                               float* __restrict__ Dsum) {     // [32][2048]
    const int bh = blockIdx.y, kt = blockIdx.x;
    const int tid = threadIdx.x, w = tid >> 6, ln = tid & 63;
    const int r16 = ln & 15, g = ln >> 4;
    const int kbase = kt * 256 + w * 64;
    const int b = bh >> 4;
    const short* kbp = k_s + ((size_t)bh * 2048 + kbase) * 64;
    const short* qp  = q_s + (size_t)bh * 2048 * 64;

    frag8 a[4][2];
#pragma unroll
    for (int mf = 0; mf < 4; mf++)
#pragma unroll
        for (int kk = 0; kk < 2; kk++)
            a[mf][kk] = *(const frag8*)(kbp + (mf * 16 + r16) * 64 + kk * 32 + g * 8);

    float dacc[4][4] = {};
    const f32x4 z = {0.f, 0.f, 0.f, 0.f};
    for (int qb = 0; qb < 2048; qb += 16) {
        frag8 bq[2];
#pragma unroll
        for (int kk = 0; kk < 2; kk++)
            bq[kk] = *(const frag8*)(qp + (size_t)(qb + r16) * 64 + kk * 32 + g * 8);
        int mv = mask[b * 2048 + qb + r16];  // this lane's q-column mask
#pragma unroll
        for (int mf = 0; mf < 4; mf++) {
            f32x4 s = MFMA16(a[mf][0], bq[0], z, 0, 0, 0);
            s = MFMA16(a[mf][1], bq[1], s, 0, 0, 0);
#pragma unroll
            for (int r = 0; r < 4; r++)
                dacc[mf][r] += mv ? __expf(s[r] * 0.125f) : 0.f;
        }
    }
    // reduce over the 16 q-columns held across lanes of each 16-lane group
#pragma unroll
    for (int mf = 0; mf < 4; mf++)
#pragma unroll
        for (int r = 0; r < 4; r++) {
#pragma unroll
            for (int off = 1; off < 16; off <<= 1)
                dacc[mf][r] += __shfl_xor(dacc[mf][r], off, 16);
        }
    if (r16 == 0) {
#pragma unroll
        for (int mf = 0; mf < 4; mf++)
#pragma unroll
            for (int r = 0; r < 4; r++)
                Dsum[(size_t)bh * 2048 + kbase + mf * 16 + g * 4 + r] = dacc[mf][r];
    }
}

// ---------- K3: vhatT[bh][d][k] = bf16(v_s[bh][k][d] / D[bh][k]) ----------
__global__ __launch_bounds__(256) void k_scale(const short* __restrict__ v_s,
                                               const float* __restrict__ Dsum,
                                               short* __restrict__ vhatT) {
    int i = blockIdx.x * blockDim.x + threadIdx.x;
    int st = gridDim.x * blockDim.x;
    const int total = 32 * 64 * 2048;
    for (; i < total; i += st) {
        int k = i & 2047;
        int d = (i >> 11) & 63;
        int bh = i >> 17;
        float Dv = Dsum[(size_t)bh * 2048 + k];
        float v = bf2f(v_s[((size_t)bh * 2048 + k) * 64 + d]);
        vhatT[i] = f2bf(v / Dv);
    }
}

// ---------- K4: apply: attn[b,q,h*64+d] = (exp(S) @ vhatT) masked ----------
__global__ __launch_bounds__(64) void k_apply(const short* __restrict__ q_s,
                                              const short* __restrict__ k_s,
                                              const short* __restrict__ vhatT, // [32][64][2048]
                                              const int* __restrict__ mask,
                                              short* __restrict__ attn) {      // [4096][1024] bf16
    const int qt = blockIdx.x, bh = blockIdx.y;
    const int b = bh >> 4, h = bh & 15;
    const int ln = threadIdx.x & 63, r16 = ln & 15, g = ln >> 4;
    __shared__ short P[64 * 32];  // P[q_local][k_local] bf16

    const short* qp = q_s + ((size_t)bh * 2048 + qt * 64) * 64;
    const short* kp = k_s + (size_t)bh * 2048 * 64;
    const short* vp = vhatT + (size_t)bh * 64 * 2048;

    frag8 qf[4][2];
#pragma unroll
    for (int nf = 0; nf < 4; nf++)
#pragma unroll
        for (int kk = 0; kk < 2; kk++)
            qf[nf][kk] = *(const frag8*)(qp + (nf * 16 + r16) * 64 + kk * 32 + g * 8);

    f32x4 o[4][4] = {};
    const f32x4 z = {0.f, 0.f, 0.f, 0.f};
    for (int kb = 0; kb < 2048; kb += 32) {
        frag8 ak[2][2];
#pragma unroll
        for (int mf2 = 0; mf2 < 2; mf2++)
#pragma unroll
            for (int kk = 0; kk < 2; kk++)
                ak[mf2][kk] = *(const frag8*)(kp + (size_t)(kb + mf2 * 16 + r16) * 64 + kk * 32 + g * 8);
        // S^T tile: rows = k (32), cols = q (64); exp; pack to P[q][k]
#pragma unroll
        for (int mf2 = 0; mf2 < 2; mf2++)
#pragma unroll
            for (int nf = 0; nf < 4; nf++) {
                f32x4 s = MFMA16(ak[mf2][0], qf[nf][0], z, 0, 0, 0);
                s = MFMA16(ak[mf2][1], qf[nf][1], s, 0, 0, 0);
                float e0 = __expf(s[0] * 0.125f), e1 = __expf(s[1] * 0.125f);
                float e2 = __expf(s[2] * 0.125f), e3 = __expf(s[3] * 0.125f);
                uint32_t lo = (uint16_t)f2bf(e0) | ((uint32_t)(uint16_t)f2bf(e1) << 16);
                uint32_t hi = (uint16_t)f2bf(e2) | ((uint32_t)(uint16_t)f2bf(e3) << 16);
                int qrow = nf * 16 + r16;
                int kcol = mf2 * 16 + g * 4;
                *(uint32_t*)&P[qrow * 32 + kcol]     = lo;
                *(uint32_t*)&P[qrow * 32 + kcol + 2] = hi;
            }
        __syncthreads();  // P writes visible
        frag8 pa[4], vb[4];
#pragma unroll
        for (int mf = 0; mf < 4; mf++)
            pa[mf] = *(const frag8*)&P[(mf * 16 + r16) * 32 + g * 8];
#pragma unroll
        for (int nf = 0; nf < 4; nf++)
            vb[nf] = *(const frag8*)(vp + (size_t)(nf * 16 + r16) * 2048 + kb + g * 8);
#pragma unroll
        for (int mf = 0; mf < 4; mf++)
#pragma unroll
            for (int nf = 0; nf < 4; nf++)
                o[mf][nf] = MFMA16(pa[mf], vb[nf], o[mf][nf], 0, 0, 0);
        __syncthreads();  // P reads done before next overwrite
    }
    // epilogue: zero masked query rows, store bf16 to [b][q][h*64+d]
#pragma unroll
    for (int mf = 0; mf < 4; mf++)
#pragma unroll
        for (int r = 0; r < 4; r++) {
            int qrow = qt * 64 + mf * 16 + g * 4 + r;
            int mv = mask[b * 2048 + qrow];
#pragma unroll
            for (int nf = 0; nf < 4; nf++) {
                int d = nf * 16 + r16;
                float val = mv ? o[mf][nf][r] : 0.f;
                attn[((size_t)(b * 2048 + qrow)) * 1024 + h * 64 + d] = f2bf(val);
            }
        }
}

// ---------- K5: final GEMM: out = attn @ Wo^T + b_O + Q ----------
__global__ __launch_bounds__(256) void k_final(const short* __restrict__ A,   // attn bf16 [4096][1024]
                                               const short* __restrict__ Bt,  // Wo bf16 [1024][1024]
                                               const float* __restrict__ bias,
                                               const float* __restrict__ Qres,
                                               float* __restrict__ out) {
    __shared__ short lA[2][4096];
    __shared__ short lB[2][4096];
    const int tid = threadIdx.x, w = tid >> 6, ln = tid & 63;
    const int wm = w >> 1, wn = w & 1, r16 = ln & 15, g = ln >> 4;
    const int tn = blockIdx.x * 128, tm = blockIdx.y * 128;
    const short* Ab = A + (size_t)tm * 1024;
    const short* Bb = Bt + (size_t)tn * 1024;

    f32x4 acc[4][4] = {};
    stage_tiles(Ab, Bb, &lA[0][0], &lB[0][0], w, ln);
    int buf = 0;
    for (int ks = 0; ks < 32; ks++) {
        __syncthreads();
        if (ks + 1 < 32)
            stage_tiles(Ab + (ks + 1) * 32, Bb + (ks + 1) * 32,
                        &lA[buf ^ 1][0], &lB[buf ^ 1][0], w, ln);
        frag8 af[4], bg[4];
#pragma unroll
        for (int mf = 0; mf < 4; mf++)
            af[mf] = *(const frag8*)&lA[buf][(wm * 64 + mf * 16 + r16) * 32 + g * 8];
#pragma unroll
        for (int nf = 0; nf < 4; nf++)
            bg[nf] = *(const frag8*)&lB[buf][(wn * 64 + nf * 16 + r16) * 32 + g * 8];
#pragma unroll
        for (int mf = 0; mf < 4; mf++)
#pragma unroll
            for (int nf = 0; nf < 4; nf++)
                acc[mf][nf] = MFMA16(af[mf], bg[nf], acc[mf][nf], 0, 0, 0);
        buf ^= 1;
    }
#pragma unroll
    for (int mf = 0; mf < 4; mf++)
#pragma unroll
        for (int nf = 0; nf < 4; nf++)
#pragma unroll
            for (int r = 0; r < 4; r++) {
                int m = tm + wm * 64 + mf * 16 + g * 4 + r;
                int n = tn + wn * 64 + nf * 16 + r16;
                float val = acc[mf][nf][r] + bias[n] + Qres[(size_t)m * 1024 + n];
                out[(size_t)m * 1024 + n] = val;
            }
}

// ---------- launch ----------
extern "C" void kernel_launch(void* const* d_in, const int* in_sizes, int n_in,
                              void* d_out, int out_size, void* d_ws, size_t ws_size,
                              hipStream_t stream) {
    const float* Qf  = (const float*)d_in[0];
    const float* Kf  = (const float*)d_in[1];
    const float* Vf  = (const float*)d_in[2];
    const int*   msk = (const int*)d_in[3];
    const float* WQ  = (const float*)d_in[4];
    const float* bQ  = (const float*)d_in[5];
    const float* WK  = (const float*)d_in[6];
    const float* bK  = (const float*)d_in[7];
    const float* WV  = (const float*)d_in[8];
    const float* bV  = (const float*)d_in[9];
    const float* WO  = (const float*)d_in[10];
    const float* bO  = (const float*)d_in[11];
    float* out = (float*)d_out;

    char* p = (char*)d_ws;
    const size_t SZ_ACT = (size_t)4096 * 1024 * 2;  // 8 MB (bf16 4096x1024)
    const size_t SZ_W   = (size_t)1024 * 1024 * 2;  // 2 MB
    short* Qb  = (short*)p; p += SZ_ACT;
    short* Kb  = (short*)p; p += SZ_ACT;
    short* Vb  = (short*)p; p += SZ_ACT;
    short* Wqb = (short*)p; p += SZ_W;
    short* Wkb = (short*)p; p += SZ_W;
    short* Wvb = (short*)p; p += SZ_W;
    short* Wob = (short*)p; p += SZ_W;
    short* q_s = (short*)p; p += SZ_ACT;
    short* k_s = (short*)p; p += SZ_ACT;
    short* v_s = (short*)p; p += SZ_ACT;
    float* Dsum = (float*)p; p += (size_t)32 * 2048 * 4;
    // reuse dead buffers after the projections:
    short* vhatT = Kb;  // dead after proj
    short* attn  = Qb;  // dead after proj

    // K0: converts
    k_cvt<<<1024, 256, 0, stream>>>(Qf, Qb, 4096 * 1024 / 4);
    k_cvt<<<1024, 256, 0, stream>>>(Kf, Kb, 4096 * 1024 / 4);
    k_cvt<<<1024, 256, 0, stream>>>(Vf, Vb, 4096 * 1024 / 4);
    k_cvt<<<512, 256, 0, stream>>>(WQ, Wqb, 1024 * 1024 / 4);
    k_cvt<<<512, 256, 0, stream>>>(WK, Wkb, 1024 * 1024 / 4);
    k_cvt<<<512, 256, 0, stream>>>(WV, Wvb, 1024 * 1024 / 4);
    k_cvt<<<512, 256, 0, stream>>>(WO, Wob, 1024 * 1024 / 4);

    // K1: projections
    dim3 ggrid(8, 32);
    k_proj<<<ggrid, 256, 0, stream>>>(Qb, Wqb, bQ, q_s);
    k_proj<<<ggrid, 256, 0, stream>>>(Kb, Wkb, bK, k_s);
    k_proj<<<ggrid, 256, 0, stream>>>(Vb, Wvb, bV, v_s);

    // K2: column softmax denominators
    k_stats<<<dim3(8, 32), 256, 0, stream>>>(k_s, q_s, msk, Dsum);

    // K3: scale + transpose V
    k_scale<<<2048, 256, 0, stream>>>(v_s, Dsum, vhatT);

    // K4: attention apply
    k_apply<<<dim3(32, 32), 64, 0, stream>>>(q_s, k_s, vhatT, msk, attn);

    // K5: output projection + bias + residual
    k_final<<<ggrid, 256, 0, stream>>>(attn, Wob, bO, Qf, out);
}

// Round 2
// 233.295 us; speedup vs baseline: 1.5296x; 1.5296x over previous
//
#include <hip/hip_runtime.h>
#include <hip/hip_bf16.h>
#include <stdint.h>

// ---------- types ----------
using frag8 = __attribute__((ext_vector_type(8))) short;   // 8 bf16 (4 VGPRs)
using f32x4 = __attribute__((ext_vector_type(4))) float;   // 4 fp32 acc

#define MFMA16 __builtin_amdgcn_mfma_f32_16x16x32_bf16

__device__ __forceinline__ short f2bf(float f) {
    union { float f; uint32_t u; } x; x.f = f;
    uint32_t r = x.u + 0x7fffu + ((x.u >> 16) & 1u);
    return (short)(r >> 16);
}
__device__ __forceinline__ float bf2f(short s) {
    union { uint32_t u; float f; } x; x.u = ((uint32_t)(uint16_t)s) << 16;
    return x.f;
}
__device__ __forceinline__ uint32_t pack2bf(float a, float b) {
    float2 t; t.x = a; t.y = b;
    __hip_bfloat162 h = __float22bfloat162_rn(t);
    union { __hip_bfloat162 h; uint32_t u; } c; c.h = h;
    return c.u;
}

// ---------- fused fp32 -> bf16 convert (7 segments) ----------
__global__ __launch_bounds__(256) void k_cvt_all(
    const float* __restrict__ s0, const float* __restrict__ s1,
    const float* __restrict__ s2, const float* __restrict__ s3,
    const float* __restrict__ s4, const float* __restrict__ s5,
    const float* __restrict__ s6,
    short* __restrict__ d0, short* __restrict__ d1, short* __restrict__ d2,
    short* __restrict__ d3, short* __restrict__ d4, short* __restrict__ d5,
    short* __restrict__ d6) {
    const int A4 = 1048576, W4 = 262144;       // float4 counts
    int i = blockIdx.x * 256 + threadIdx.x;
    int st = gridDim.x * 256;
    const int total = 3 * A4 + 4 * W4;
    for (; i < total; i += st) {
        const float* s; short* d; int j;
        if (i < A4)            { s = s0; d = d0; j = i; }
        else if (i < 2 * A4)   { s = s1; d = d1; j = i - A4; }
        else if (i < 3 * A4)   { s = s2; d = d2; j = i - 2 * A4; }
        else {
            int t = i - 3 * A4; int seg = t / W4; j = t - seg * W4;
            s = seg == 0 ? s3 : seg == 1 ? s4 : seg == 2 ? s5 : s6;
            d = seg == 0 ? d3 : seg == 1 ? d4 : seg == 2 ? d5 : d6;
        }
        float4 v = reinterpret_cast<const float4*>(s)[j];
        ushort4 o;
        o.x = (uint16_t)f2bf(v.x); o.y = (uint16_t)f2bf(v.y);
        o.z = (uint16_t)f2bf(v.z); o.w = (uint16_t)f2bf(v.w);
        reinterpret_cast<ushort4*>(d)[j] = o;
    }
}

// ---------- swizzled staging: [64 rows][128B], XOR chunk ^= row&7 ----------
// LDS layout is LINEAR (chunk*16B); the XOR permutation is applied to the
// GLOBAL source address (m173 pattern), and again on every ds_read.
__device__ __forceinline__ void stage64x128(const short* __restrict__ g, int rs,
                                            short* lds, int tid) {
#pragma unroll
    for (int j = 0; j < 2; j++) {
        int chunk = j * 256 + tid;            // 0..511
        int row = chunk >> 3, c = chunk & 7;
        int sc = c ^ (row & 7);
        __builtin_amdgcn_global_load_lds(
            (const __attribute__((address_space(1))) uint32_t*)(g + (size_t)row * rs + sc * 8),
            (__attribute__((address_space(3))) uint32_t*)(lds + (j * 256 + (tid & 192)) * 8),
            16, 0, 0);
    }
}
// swizzled b128 read: logical (row, 16B-chunk cc)
__device__ __forceinline__ frag8 ldswz(const short* lds, int row, int cc) {
    return *(const frag8*)(lds + row * 64 + ((cc ^ (row & 7)) << 3));
}

// ---------- GEMM staging (m97-style, linear) ----------
__device__ __forceinline__ void stage_tiles(const short* __restrict__ As,
                                            const short* __restrict__ Bs,
                                            short* lA, short* lB,
                                            int w, int ln) {
#pragma unroll
    for (int j = 0; j < 2; j++) {
        int cb = (w * 2 + j) * 64;
        int c  = cb + ln;
        int row = c >> 2, c8 = c & 3;
        __builtin_amdgcn_global_load_lds(
            (const __attribute__((address_space(1))) uint32_t*)(As + row * 1024 + c8 * 8),
            (__attribute__((address_space(3))) uint32_t*)(lA + cb * 8), 16, 0, 0);
        __builtin_amdgcn_global_load_lds(
            (const __attribute__((address_space(1))) uint32_t*)(Bs + row * 1024 + c8 * 8),
            (__attribute__((address_space(3))) uint32_t*)(lB + cb * 8), 16, 0, 0);
    }
}

// ---------- K1: projection GEMM -> dst[b,h,seq,64] bf16 ----------
__global__ __launch_bounds__(256) void k_proj(const short* __restrict__ A,
                                              const short* __restrict__ Bt,
                                              const float* __restrict__ bias,
                                              short* __restrict__ dst) {
    __shared__ short lA[2][4096];
    __shared__ short lB[2][4096];
    const int tid = threadIdx.x, w = tid >> 6, ln = tid & 63;
    const int wm = w >> 1, wn = w & 1, r16 = ln & 15, g = ln >> 4;
    const int tn = blockIdx.x * 128, tm = blockIdx.y * 128;
    const short* Ab = A + (size_t)tm * 1024;
    const short* Bb = Bt + (size_t)tn * 1024;

    f32x4 acc[4][4] = {};
    stage_tiles(Ab, Bb, &lA[0][0], &lB[0][0], w, ln);
    int buf = 0;
    for (int ks = 0; ks < 32; ks++) {
        __syncthreads();
        if (ks + 1 < 32)
            stage_tiles(Ab + (ks + 1) * 32, Bb + (ks + 1) * 32,
                        &lA[buf ^ 1][0], &lB[buf ^ 1][0], w, ln);
        frag8 af[4], bg[4];
#pragma unroll
        for (int mf = 0; mf < 4; mf++)
            af[mf] = *(const frag8*)&lA[buf][(wm * 64 + mf * 16 + r16) * 32 + g * 8];
#pragma unroll
        for (int nf = 0; nf < 4; nf++)
            bg[nf] = *(const frag8*)&lB[buf][(wn * 64 + nf * 16 + r16) * 32 + g * 8];
#pragma unroll
        for (int mf = 0; mf < 4; mf++)
#pragma unroll
            for (int nf = 0; nf < 4; nf++)
                acc[mf][nf] = MFMA16(af[mf], bg[nf], acc[mf][nf], 0, 0, 0);
        buf ^= 1;
    }
#pragma unroll
    for (int mf = 0; mf < 4; mf++)
#pragma unroll
        for (int nf = 0; nf < 4; nf++)
#pragma unroll
            for (int r = 0; r < 4; r++) {
                int m = tm + wm * 64 + mf * 16 + g * 4 + r;
                int n = tn + wn * 64 + nf * 16 + r16;
                float val = acc[mf][nf][r] + bias[n];
                int b = m >> 11, seq = m & 2047, h = n >> 6, d = n & 63;
                dst[((size_t)(b * 16 + h) * 2048 + seq) * 64 + d] = f2bf(val);
            }
}

// ---------- K2: D[bh][k] = sum_q(masked) exp(S[q,k]/8) ----------
// 4 waves; wave owns 32 k-rows (K frags hoisted); q swept in 64-chunks in LDS.
__global__ __launch_bounds__(256) void k_stats(const short* __restrict__ k_s,
                                               const short* __restrict__ q_s,
                                               const int* __restrict__ mask,
                                               float* __restrict__ Dsum) {
    __shared__ short lQ[2][4096];
    const int wg = blockIdx.x;
    const int lin = (wg & 7) * 64 + (wg >> 3);     // XCD swizzle: bh contiguous per XCD
    const int bh = lin >> 4, kt = lin & 15;
    const int b = bh >> 4;
    const int tid = threadIdx.x, w = tid >> 6, ln = tid & 63;
    const int r16 = ln & 15, g = ln >> 4;
    const int kbase = kt * 128 + w * 32;

    // hoist K fragments (wave's 32 k rows)
    const short* kp = k_s + ((size_t)bh * 2048 + kbase) * 64;
    frag8 kf[2][2];
#pragma unroll
    for (int mf = 0; mf < 2; mf++)
#pragma unroll
        for (int kk = 0; kk < 2; kk++)
            kf[mf][kk] = *(const frag8*)(kp + (mf * 16 + r16) * 64 + kk * 32 + g * 8);

    const short* qsp = q_s + (size_t)bh * 2048 * 64;
    float dacc[2][4] = {};
    const f32x4 z = {0.f, 0.f, 0.f, 0.f};

    stage64x128(qsp, 64, &lQ[0][0], tid);
    int buf = 0;
    for (int qb = 0; qb < 2048; qb += 64) {
        __syncthreads();
        if (qb + 64 < 2048)
            stage64x128(qsp + (size_t)(qb + 64) * 64, 64, &lQ[buf ^ 1][0], tid);
        const short* Qc = &lQ[buf][0];
#pragma unroll
        for (int nf = 0; nf < 4; nf++) {
            float fm = (float)mask[b * 2048 + qb + nf * 16 + r16];
            frag8 bq0 = ldswz(Qc, nf * 16 + r16, g);
            frag8 bq1 = ldswz(Qc, nf * 16 + r16, 4 + g);
#pragma unroll
            for (int mf = 0; mf < 2; mf++) {
                f32x4 s = MFMA16(kf[mf][0], bq0, z, 0, 0, 0);
                s = MFMA16(kf[mf][1], bq1, s, 0, 0, 0);
#pragma unroll
                for (int r = 0; r < 4; r++)
                    dacc[mf][r] += fm * __expf(s[r] * 0.125f);
            }
        }
        buf ^= 1;
    }
    // reduce the 16 q-columns across each 16-lane group
#pragma unroll
    for (int mf = 0; mf < 2; mf++)
#pragma unroll
        for (int r = 0; r < 4; r++) {
            float v = dacc[mf][r];
#pragma unroll
            for (int off = 1; off < 16; off <<= 1)
                v += __shfl_xor(v, off, 16);
            dacc[mf][r] = v;
        }
    if (r16 == 0) {
#pragma unroll
        for (int mf = 0; mf < 2; mf++)
#pragma unroll
            for (int r = 0; r < 4; r++)
                Dsum[(size_t)bh * 2048 + kbase + mf * 16 + g * 4 + r] = dacc[mf][r];
    }
}

// ---------- K3: vhatT[bh][d][k] = bf16(v_s[bh][k][d] / D[bh][k]) ----------
__global__ __launch_bounds__(256) void k_scale(const short* __restrict__ v_s,
                                               const float* __restrict__ Dsum,
                                               short* __restrict__ vhatT) {
    int i = blockIdx.x * blockDim.x + threadIdx.x;
    int st = gridDim.x * blockDim.x;
    const int total = 32 * 64 * 2048;
    for (; i < total; i += st) {
        int k = i & 2047;
        int d = (i >> 11) & 63;
        int bh = i >> 17;
        float Dv = Dsum[(size_t)bh * 2048 + k];
        float v = bf2f(v_s[((size_t)bh * 2048 + k) * 64 + d]);
        vhatT[i] = f2bf(v / Dv);
    }
}

// ---------- K4: apply: attn = (exp(S/8) @ vhatT), masked rows zeroed ----------
// 4 waves; block owns 128 q (wave: 32 q, Q hoisted); k swept in 64-chunks,
// K + vhat double-buffered in LDS (XOR swizzle); P per-wave via LDS.
__global__ __launch_bounds__(256) void k_apply(const short* __restrict__ q_s,
                                               const short* __restrict__ k_s,
                                               const short* __restrict__ vhatT,
                                               const int* __restrict__ mask,
                                               short* __restrict__ attn) {
    __shared__ short lK[2][4096];
    __shared__ short lV[2][4096];
    __shared__ short lP[128 * 64];
    const int wg = blockIdx.x;
    const int lin = (wg & 7) * 64 + (wg >> 3);     // XCD swizzle
    const int bh = lin >> 4, qt = lin & 15;
    const int b = bh >> 4, h = bh & 15;
    const int tid = threadIdx.x, w = tid >> 6, ln = tid & 63;
    const int r16 = ln & 15, g = ln >> 4;

    // hoist Q fragments (wave's 32 q rows)
    const short* qp = q_s + ((size_t)bh * 2048 + qt * 128 + w * 32) * 64;
    frag8 qf[2][2];
#pragma unroll
    for (int nf = 0; nf < 2; nf++)
#pragma unroll
        for (int kk = 0; kk < 2; kk++)
            qf[nf][kk] = *(const frag8*)(qp + (nf * 16 + r16) * 64 + kk * 32 + g * 8);

    const short* kp = k_s + (size_t)bh * 2048 * 64;
    const short* vp = vhatT + (size_t)bh * 64 * 2048;

    f32x4 oacc[2][4] = {};
    const f32x4 z = {0.f, 0.f, 0.f, 0.f};

    stage64x128(kp, 64, &lK[0][0], tid);
    stage64x128(vp, 2048, &lV[0][0], tid);
    int buf = 0;
    for (int kb = 0; kb < 2048; kb += 64) {
        __syncthreads();
        if (kb + 64 < 2048) {
            stage64x128(kp + (size_t)(kb + 64) * 64, 64, &lK[buf ^ 1][0], tid);
            stage64x128(vp + kb + 64, 2048, &lV[buf ^ 1][0], tid);
        }
        const short* Kc = &lK[buf][0];
        const short* Vc = &lV[buf][0];
        // S^T (64k x 32q) -> exp -> P[q][k]
#pragma unroll
        for (int nf = 0; nf < 2; nf++) {
            const int prow = w * 32 + nf * 16 + r16;
            const int rx = prow & 7;
#pragma unroll
            for (int mf2 = 0; mf2 < 4; mf2++) {
                f32x4 s = z;
#pragma unroll
                for (int kk = 0; kk < 2; kk++)
                    s = MFMA16(ldswz(Kc, mf2 * 16 + r16, kk * 4 + g), qf[nf][kk], s, 0, 0, 0);
                float e0 = __expf(s[0] * 0.125f), e1 = __expf(s[1] * 0.125f);
                float e2 = __expf(s[2] * 0.125f), e3 = __expf(s[3] * 0.125f);
                uint2 pk;
                pk.x = pack2bf(e0, e1);
                pk.y = pack2bf(e2, e3);
                int o = mf2 * 32 + g * 8;                    // byte offset in 128B row
                int addr = prow * 128 + ((((o >> 4) ^ rx)) << 4) + (o & 15);
                *(uint2*)((char*)lP + addr) = pk;
            }
        }
        // PV: oacc[q][d] += P[q][k] * vhat[d][k]
        frag8 vb[4][2];
#pragma unroll
        for (int nf = 0; nf < 4; nf++)
#pragma unroll
            for (int kk = 0; kk < 2; kk++)
                vb[nf][kk] = ldswz(Vc, nf * 16 + r16, kk * 4 + g);
#pragma unroll
        for (int mf = 0; mf < 2; mf++) {
            const int prow = w * 32 + mf * 16 + r16;
            const int rx = prow & 7;
            frag8 pa[2];
#pragma unroll
            for (int kk = 0; kk < 2; kk++)
                pa[kk] = *(const frag8*)((char*)lP + prow * 128 + (((kk * 4 + g) ^ rx) << 4));
#pragma unroll
            for (int nf = 0; nf < 4; nf++)
#pragma unroll
                for (int kk = 0; kk < 2; kk++)
                    oacc[mf][nf] = MFMA16(pa[kk], vb[nf][kk], oacc[mf][nf], 0, 0, 0);
        }
        buf ^= 1;
    }
    // epilogue: zero masked q rows, store bf16
#pragma unroll
    for (int mf = 0; mf < 2; mf++)
#pragma unroll
        for (int r = 0; r < 4; r++) {
            int q = qt * 128 + w * 32 + mf * 16 + g * 4 + r;
            int mv = mask[b * 2048 + q];
#pragma unroll
            for (int nf = 0; nf < 4; nf++) {
                int d = nf * 16 + r16;
                float val = mv ? oacc[mf][nf][r] : 0.f;
                attn[((size_t)(b * 2048 + q)) * 1024 + h * 64 + d] = f2bf(val);
            }
        }
}

// ---------- K5: out = attn @ Wo^T + b_O + Q ----------
__global__ __launch_bounds__(256) void k_final(const short* __restrict__ A,
                                               const short* __restrict__ Bt,
                                               const float* __restrict__ bias,
                                               const float* __restrict__ Qres,
                                               float* __restrict__ out) {
    __shared__ short lA[2][4096];
    __shared__ short lB[2][4096];
    const int tid = threadIdx.x, w = tid >> 6, ln = tid & 63;
    const int wm = w >> 1, wn = w & 1, r16 = ln & 15, g = ln >> 4;
    const int tn = blockIdx.x * 128, tm = blockIdx.y * 128;
    const short* Ab = A + (size_t)tm * 1024;
    const short* Bb = Bt + (size_t)tn * 1024;

    f32x4 acc[4][4] = {};
    stage_tiles(Ab, Bb, &lA[0][0], &lB[0][0], w, ln);
    int buf = 0;
    for (int ks = 0; ks < 32; ks++) {
        __syncthreads();
        if (ks + 1 < 32)
            stage_tiles(Ab + (ks + 1) * 32, Bb + (ks + 1) * 32,
                        &lA[buf ^ 1][0], &lB[buf ^ 1][0], w, ln);
        frag8 af[4], bg[4];
#pragma unroll
        for (int mf = 0; mf < 4; mf++)
            af[mf] = *(const frag8*)&lA[buf][(wm * 64 + mf * 16 + r16) * 32 + g * 8];
#pragma unroll
        for (int nf = 0; nf < 4; nf++)
            bg[nf] = *(const frag8*)&lB[buf][(wn * 64 + nf * 16 + r16) * 32 + g * 8];
#pragma unroll
        for (int mf = 0; mf < 4; mf++)
#pragma unroll
            for (int nf = 0; nf < 4; nf++)
                acc[mf][nf] = MFMA16(af[mf], bg[nf], acc[mf][nf], 0, 0, 0);
        buf ^= 1;
    }
#pragma unroll
    for (int mf = 0; mf < 4; mf++)
#pragma unroll
        for (int nf = 0; nf < 4; nf++)
#pragma unroll
            for (int r = 0; r < 4; r++) {
                int m = tm + wm * 64 + mf * 16 + g * 4 + r;
                int n = tn + wn * 64 + nf * 16 + r16;
                float val = acc[mf][nf][r] + bias[n] + Qres[(size_t)m * 1024 + n];
                out[(size_t)m * 1024 + n] = val;
            }
}

// ---------- launch ----------
extern "C" void kernel_launch(void* const* d_in, const int* in_sizes, int n_in,
                              void* d_out, int out_size, void* d_ws, size_t ws_size,
                              hipStream_t stream) {
    (void)in_sizes; (void)n_in; (void)out_size; (void)ws_size;
    const float* Qf  = (const float*)d_in[0];
    const float* Kf  = (const float*)d_in[1];
    const float* Vf  = (const float*)d_in[2];
    const int*   msk = (const int*)d_in[3];
    const float* WQ  = (const float*)d_in[4];
    const float* bQ  = (const float*)d_in[5];
    const float* WK  = (const float*)d_in[6];
    const float* bK  = (const float*)d_in[7];
    const float* WV  = (const float*)d_in[8];
    const float* bV  = (const float*)d_in[9];
    const float* WO  = (const float*)d_in[10];
    const float* bO  = (const float*)d_in[11];
    float* out = (float*)d_out;

    char* p = (char*)d_ws;
    const size_t SZ_ACT = (size_t)4096 * 1024 * 2;  // 8 MB bf16
    const size_t SZ_W   = (size_t)1024 * 1024 * 2;  // 2 MB
    short* Qb  = (short*)p; p += SZ_ACT;
    short* Kb  = (short*)p; p += SZ_ACT;
    short* Vb  = (short*)p; p += SZ_ACT;
    short* Wqb = (short*)p; p += SZ_W;
    short* Wkb = (short*)p; p += SZ_W;
    short* Wvb = (short*)p; p += SZ_W;
    short* Wob = (short*)p; p += SZ_W;
    short* q_s = (short*)p; p += SZ_ACT;
    short* k_s = (short*)p; p += SZ_ACT;
    short* v_s = (short*)p; p += SZ_ACT;
    float* Dsum = (float*)p; p += (size_t)32 * 2048 * 4;
    short* vhatT = Kb;  // dead after proj
    short* attn  = Qb;  // dead after proj

    // K0: fused converts
    k_cvt_all<<<4096, 256, 0, stream>>>(Qf, Kf, Vf, WQ, WK, WV, WO,
                                        Qb, Kb, Vb, Wqb, Wkb, Wvb, Wob);

    // K1: projections
    dim3 ggrid(8, 32);
    k_proj<<<ggrid, 256, 0, stream>>>(Qb, Wqb, bQ, q_s);
    k_proj<<<ggrid, 256, 0, stream>>>(Kb, Wkb, bK, k_s);
    k_proj<<<ggrid, 256, 0, stream>>>(Vb, Wvb, bV, v_s);

    // K2: column softmax denominators
    k_stats<<<512, 256, 0, stream>>>(k_s, q_s, msk, Dsum);

    // K3: scale + transpose V
    k_scale<<<2048, 256, 0, stream>>>(v_s, Dsum, vhatT);

    // K4: attention apply
    k_apply<<<512, 256, 0, stream>>>(q_s, k_s, vhatT, msk, attn);

    // K5: output projection + bias + residual
    k_final<<<ggrid, 256, 0, stream>>>(attn, Wob, bO, Qf, out);
}

// Round 3
// 173.561 us; speedup vs baseline: 2.0560x; 1.3442x over previous
//
#include <hip/hip_runtime.h>
#include <hip/hip_bf16.h>
#include <stdint.h>

// ---------- types ----------
using frag8 = __attribute__((ext_vector_type(8))) short;   // 8 bf16 (4 VGPRs)
using f32x4 = __attribute__((ext_vector_type(4))) float;   // 4 fp32 acc

#define MFMA16 __builtin_amdgcn_mfma_f32_16x16x32_bf16

#if __has_builtin(__builtin_amdgcn_exp2f)
#define EXP2F(x) __builtin_amdgcn_exp2f(x)
#else
#define EXP2F(x) __expf((x) * 0.6931471805599453f)
#endif
#if __has_builtin(__builtin_amdgcn_rcpf)
#define RCPF(x) __builtin_amdgcn_rcpf(x)
#else
#define RCPF(x) (1.0f / (x))
#endif

// S' = (q.k)/8 * log2(e): folded into Q projection output
#define SCALE_Q 0.18033688011112042f

__device__ __forceinline__ short f2bf(float f) {
    union { float f; uint32_t u; } x; x.f = f;
    uint32_t r = x.u + 0x7fffu + ((x.u >> 16) & 1u);
    return (short)(r >> 16);
}
__device__ __forceinline__ float bf2f(short s) {
    union { uint32_t u; float f; } x; x.u = ((uint32_t)(uint16_t)s) << 16;
    return x.f;
}
__device__ __forceinline__ uint32_t pack2bf(float a, float b) {
    float2 t; t.x = a; t.y = b;
    __hip_bfloat162 h = __float22bfloat162_rn(t);
    union { __hip_bfloat162 h; uint32_t u; } c; c.h = h;
    return c.u;
}

// ---------- fused fp32 -> bf16 convert (7 segments) ----------
__global__ __launch_bounds__(256) void k_cvt_all(
    const float* __restrict__ s0, const float* __restrict__ s1,
    const float* __restrict__ s2, const float* __restrict__ s3,
    const float* __restrict__ s4, const float* __restrict__ s5,
    const float* __restrict__ s6,
    short* __restrict__ d0, short* __restrict__ d1, short* __restrict__ d2,
    short* __restrict__ d3, short* __restrict__ d4, short* __restrict__ d5,
    short* __restrict__ d6) {
    const int A4 = 1048576, W4 = 262144;       // float4 counts
    int i = blockIdx.x * 256 + threadIdx.x;
    int st = gridDim.x * 256;
    const int total = 3 * A4 + 4 * W4;
    for (; i < total; i += st) {
        const float* s; short* d; int j;
        if (i < A4)            { s = s0; d = d0; j = i; }
        else if (i < 2 * A4)   { s = s1; d = d1; j = i - A4; }
        else if (i < 3 * A4)   { s = s2; d = d2; j = i - 2 * A4; }
        else {
            int t = i - 3 * A4; int seg = t / W4; j = t - seg * W4;
            s = seg == 0 ? s3 : seg == 1 ? s4 : seg == 2 ? s5 : s6;
            d = seg == 0 ? d3 : seg == 1 ? d4 : seg == 2 ? d5 : d6;
        }
        float4 v = reinterpret_cast<const float4*>(s)[j];
        ushort4 o;
        o.x = (uint16_t)f2bf(v.x); o.y = (uint16_t)f2bf(v.y);
        o.z = (uint16_t)f2bf(v.z); o.w = (uint16_t)f2bf(v.w);
        reinterpret_cast<ushort4*>(d)[j] = o;
    }
}

// ---------- swizzled staging: [64 rows][128B], XOR chunk ^= row&7 ----------
// LDS dest is LINEAR; XOR applied to the GLOBAL source address (m173) and
// again on every ds_read, so reads see the logical layout conflict-free.
__device__ __forceinline__ void stage64x128(const short* __restrict__ g, int rs,
                                            short* lds, int tid) {
#pragma unroll
    for (int j = 0; j < 2; j++) {
        int chunk = j * 256 + tid;            // 0..511
        int row = chunk >> 3, c = chunk & 7;
        int sc = c ^ (row & 7);
        __builtin_amdgcn_global_load_lds(
            (const __attribute__((address_space(1))) uint32_t*)(g + (size_t)row * rs + sc * 8),
            (__attribute__((address_space(3))) uint32_t*)(lds + (j * 256 + (tid & 192)) * 8),
            16, 0, 0);
    }
}
// swizzled b128 read: logical (row, 16B-chunk cc)
__device__ __forceinline__ frag8 ldswz(const short* lds, int row, int cc) {
    return *(const frag8*)(lds + row * 64 + ((cc ^ (row & 7)) << 3));
}

// ---------- GEMM staging (m97-style, linear) ----------
__device__ __forceinline__ void stage_tiles(const short* __restrict__ As,
                                            const short* __restrict__ Bs,
                                            short* lA, short* lB,
                                            int w, int ln) {
#pragma unroll
    for (int j = 0; j < 2; j++) {
        int cb = (w * 2 + j) * 64;
        int c  = cb + ln;
        int row = c >> 2, c8 = c & 3;
        __builtin_amdgcn_global_load_lds(
            (const __attribute__((address_space(1))) uint32_t*)(As + row * 1024 + c8 * 8),
            (__attribute__((address_space(3))) uint32_t*)(lA + cb * 8), 16, 0, 0);
        __builtin_amdgcn_global_load_lds(
            (const __attribute__((address_space(1))) uint32_t*)(Bs + row * 1024 + c8 * 8),
            (__attribute__((address_space(3))) uint32_t*)(lB + cb * 8), 16, 0, 0);
    }
}

// ---------- K1: fused QKV projection -> dst[b,h,seq,64] bf16 (scaled) ----------
__global__ __launch_bounds__(256) void k_proj3(const short* __restrict__ A0,
                                               const short* __restrict__ A1,
                                               const short* __restrict__ A2,
                                               const short* __restrict__ B0,
                                               const short* __restrict__ B1,
                                               const short* __restrict__ B2,
                                               const float* __restrict__ bias0,
                                               const float* __restrict__ bias1,
                                               const float* __restrict__ bias2,
                                               short* __restrict__ dst0,
                                               short* __restrict__ dst1,
                                               short* __restrict__ dst2) {
    __shared__ short lA[2][4096];
    __shared__ short lB[2][4096];
    const int z = blockIdx.z;
    const short* A  = z == 0 ? A0 : z == 1 ? A1 : A2;
    const short* Bt = z == 0 ? B0 : z == 1 ? B1 : B2;
    const float* bias = z == 0 ? bias0 : z == 1 ? bias1 : bias2;
    short* dst = z == 0 ? dst0 : z == 1 ? dst1 : dst2;
    const float scale = z == 0 ? SCALE_Q : 1.0f;

    const int tid = threadIdx.x, w = tid >> 6, ln = tid & 63;
    const int wm = w >> 1, wn = w & 1, r16 = ln & 15, g = ln >> 4;
    const int tn = blockIdx.x * 128, tm = blockIdx.y * 128;
    const short* Ab = A + (size_t)tm * 1024;
    const short* Bb = Bt + (size_t)tn * 1024;

    f32x4 acc[4][4] = {};
    stage_tiles(Ab, Bb, &lA[0][0], &lB[0][0], w, ln);
    int buf = 0;
    for (int ks = 0; ks < 32; ks++) {
        __syncthreads();
        if (ks + 1 < 32)
            stage_tiles(Ab + (ks + 1) * 32, Bb + (ks + 1) * 32,
                        &lA[buf ^ 1][0], &lB[buf ^ 1][0], w, ln);
        frag8 af[4], bg[4];
#pragma unroll
        for (int mf = 0; mf < 4; mf++)
            af[mf] = *(const frag8*)&lA[buf][(wm * 64 + mf * 16 + r16) * 32 + g * 8];
#pragma unroll
        for (int nf = 0; nf < 4; nf++)
            bg[nf] = *(const frag8*)&lB[buf][(wn * 64 + nf * 16 + r16) * 32 + g * 8];
#pragma unroll
        for (int mf = 0; mf < 4; mf++)
#pragma unroll
            for (int nf = 0; nf < 4; nf++)
                acc[mf][nf] = MFMA16(af[mf], bg[nf], acc[mf][nf], 0, 0, 0);
        buf ^= 1;
    }
#pragma unroll
    for (int mf = 0; mf < 4; mf++)
#pragma unroll
        for (int nf = 0; nf < 4; nf++)
#pragma unroll
            for (int r = 0; r < 4; r++) {
                int m = tm + wm * 64 + mf * 16 + g * 4 + r;
                int n = tn + wn * 64 + nf * 16 + r16;
                float val = (acc[mf][nf][r] + bias[n]) * scale;
                int b = m >> 11, seq = m & 2047, h = n >> 6, d = n & 63;
                dst[((size_t)(b * 16 + h) * 2048 + seq) * 64 + d] = f2bf(val);
            }
}

// ---------- K2: stats + fused v-scale ----------
// Block owns (bh, 64 k rows). Wave owns 16 k (K frags hoisted); q swept in
// 64-chunks (LDS dbuf). Then vhatT[bh][d][krange] = v/D via LDS transpose.
__global__ __launch_bounds__(256, 4) void k_stats(const short* __restrict__ k_s,
                                                  const short* __restrict__ q_s,
                                                  const int* __restrict__ mask,
                                                  const short* __restrict__ v_s,
                                                  short* __restrict__ vhatT) {
    __shared__ short lQ[2][4096];
    __shared__ float lD[64];
    __shared__ short lT[64 * 70];               // v tile [k][d], row stride 70
    const int wg = blockIdx.x;
    const int lin = (wg & 7) * 128 + (wg >> 3); // XCD swizzle
    const int bh = lin >> 5, kt = lin & 31;
    const int b = bh >> 4;
    const int tid = threadIdx.x, w = tid >> 6, ln = tid & 63;
    const int r16 = ln & 15, g = ln >> 4;
    const int kbase = kt * 64 + w * 16;

    const short* kp = k_s + ((size_t)bh * 2048 + kbase) * 64;
    frag8 kf[2];
#pragma unroll
    for (int kk = 0; kk < 2; kk++)
        kf[kk] = *(const frag8*)(kp + r16 * 64 + kk * 32 + g * 8);

    const short* qsp = q_s + (size_t)bh * 2048 * 64;
    float dacc[4] = {};
    const f32x4 z4 = {0.f, 0.f, 0.f, 0.f};

    stage64x128(qsp, 64, &lQ[0][0], tid);
    int buf = 0;
    for (int qb = 0; qb < 2048; qb += 64) {
        __syncthreads();
        if (qb + 64 < 2048)
            stage64x128(qsp + (size_t)(qb + 64) * 64, 64, &lQ[buf ^ 1][0], tid);
        const short* Qc = &lQ[buf][0];
#pragma unroll
        for (int nf = 0; nf < 4; nf++) {
            float fm = (float)mask[b * 2048 + qb + nf * 16 + r16];
            frag8 bq0 = ldswz(Qc, nf * 16 + r16, g);
            frag8 bq1 = ldswz(Qc, nf * 16 + r16, 4 + g);
            f32x4 s = MFMA16(kf[0], bq0, z4, 0, 0, 0);
            s = MFMA16(kf[1], bq1, s, 0, 0, 0);
#pragma unroll
            for (int r = 0; r < 4; r++)
                dacc[r] += fm * EXP2F(s[r]);
        }
        buf ^= 1;
    }
    // reduce over the 16 q-columns in each 16-lane group
#pragma unroll
    for (int r = 0; r < 4; r++) {
        float v = dacc[r];
#pragma unroll
        for (int off = 1; off < 16; off <<= 1)
            v += __shfl_xor(v, off, 16);
        dacc[r] = v;
    }
    if (r16 == 0) {
#pragma unroll
        for (int r = 0; r < 4; r++)
            lD[w * 16 + g * 4 + r] = RCPF(dacc[r]);
    }
    // stage v tile [64k][64d] into lT (stride 70)
    const short* vrow = v_s + ((size_t)bh * 2048 + kt * 64) * 64;
#pragma unroll
    for (int i = 0; i < 4; i++) {
        int idx4 = i * 256 + tid;               // ushort4 units
        int row = idx4 >> 4, c4 = idx4 & 15;
        uint2 u = *(const uint2*)(vrow + (size_t)row * 64 + c4 * 4);
        *(uint32_t*)&lT[row * 70 + c4 * 4]     = u.x;
        *(uint32_t*)&lT[row * 70 + c4 * 4 + 2] = u.y;
    }
    __syncthreads();
    // transposed write: vhatT[bh][d][kt*64 + kc*16 .. +16]
    {
        int d = tid >> 2, kc = tid & 3;
        short* dstp = vhatT + ((size_t)bh * 64 + d) * 2048 + kt * 64 + kc * 16;
        uint32_t wd[8];
#pragma unroll
        for (int j2 = 0; j2 < 8; j2++) {
            int k0 = kc * 16 + j2 * 2;
            float v0 = bf2f(lT[k0 * 70 + d]) * lD[k0];
            float v1 = bf2f(lT[(k0 + 1) * 70 + d]) * lD[k0 + 1];
            wd[j2] = pack2bf(v0, v1);
        }
        uint4 o0 = {wd[0], wd[1], wd[2], wd[3]};
        uint4 o1 = {wd[4], wd[5], wd[6], wd[7]};
        *(uint4*)dstp = o0;
        *((uint4*)dstp + 1) = o1;
    }
}

// ---------- K4: apply: attn = (exp2(S') @ vhatT), masked rows zeroed ----------
// Block owns (bh, 64 q). Wave owns 16 q (Q hoisted). k swept in 64-chunks,
// K + vhat double-buffered in LDS (XOR swizzle); P per-wave via LDS.
__global__ __launch_bounds__(256, 4) void k_apply(const short* __restrict__ q_s,
                                                  const short* __restrict__ k_s,
                                                  const short* __restrict__ vhatT,
                                                  const int* __restrict__ mask,
                                                  short* __restrict__ attn) {
    __shared__ short lK[2][4096];
    __shared__ short lV[2][4096];
    __shared__ short lP[64 * 64];               // P[q][k] bf16, chunk-XOR swizzled
    const int wg = blockIdx.x;
    const int lin = (wg & 7) * 128 + (wg >> 3); // XCD swizzle
    const int bh = lin >> 5, qt = lin & 31;
    const int b = bh >> 4, h = bh & 15;
    const int tid = threadIdx.x, w = tid >> 6, ln = tid & 63;
    const int r16 = ln & 15, g = ln >> 4;

    const short* qp = q_s + ((size_t)bh * 2048 + qt * 64 + w * 16) * 64;
    frag8 qf[2];
#pragma unroll
    for (int kk = 0; kk < 2; kk++)
        qf[kk] = *(const frag8*)(qp + r16 * 64 + kk * 32 + g * 8);

    const short* kp = k_s + (size_t)bh * 2048 * 64;
    const short* vp = vhatT + (size_t)bh * 64 * 2048;

    f32x4 oacc[4] = {};
    const f32x4 z4 = {0.f, 0.f, 0.f, 0.f};
    const int prow = w * 16 + r16, rx = prow & 7;

    stage64x128(kp, 64, &lK[0][0], tid);
    stage64x128(vp, 2048, &lV[0][0], tid);
    int buf = 0;
    for (int kb = 0; kb < 2048; kb += 64) {
        __syncthreads();
        if (kb + 64 < 2048) {
            stage64x128(kp + (size_t)(kb + 64) * 64, 64, &lK[buf ^ 1][0], tid);
            stage64x128(vp + kb + 64, 2048, &lV[buf ^ 1][0], tid);
        }
        const short* Kc = &lK[buf][0];
        const short* Vc = &lV[buf][0];
        // S^T (64k x 16q per wave) -> exp2 -> P[q][k]
#pragma unroll
        for (int mf2 = 0; mf2 < 4; mf2++) {
            f32x4 s = z4;
#pragma unroll
            for (int kk = 0; kk < 2; kk++)
                s = MFMA16(ldswz(Kc, mf2 * 16 + r16, kk * 4 + g), qf[kk], s, 0, 0, 0);
            float e0 = EXP2F(s[0]), e1 = EXP2F(s[1]);
            float e2 = EXP2F(s[2]), e3 = EXP2F(s[3]);
            uint2 pk;
            pk.x = pack2bf(e0, e1);
            pk.y = pack2bf(e2, e3);
            int o = mf2 * 32 + g * 8;           // byte offset in 128B P row
            int addr = prow * 128 + (((o >> 4) ^ rx) << 4) + (o & 15);
            *(uint2*)((char*)lP + addr) = pk;
        }
        // PV: oacc[d] += P[q][k] * vhat[d][k]   (same-wave P RAW: DS in-order)
        frag8 pa[2];
#pragma unroll
        for (int kk = 0; kk < 2; kk++)
            pa[kk] = *(const frag8*)((char*)lP + prow * 128 + (((kk * 4 + g) ^ rx) << 4));
#pragma unroll
        for (int nf = 0; nf < 4; nf++)
#pragma unroll
            for (int kk = 0; kk < 2; kk++)
                oacc[nf] = MFMA16(pa[kk], ldswz(Vc, nf * 16 + r16, kk * 4 + g), oacc[nf], 0, 0, 0);
        buf ^= 1;
    }
    // epilogue: zero masked q rows, store bf16
#pragma unroll
    for (int r = 0; r < 4; r++) {
        int q = qt * 64 + w * 16 + g * 4 + r;
        int mv = mask[b * 2048 + q];
#pragma unroll
        for (int nf = 0; nf < 4; nf++) {
            int d = nf * 16 + r16;
            float val = mv ? oacc[nf][r] : 0.f;
            attn[((size_t)(b * 2048 + q)) * 1024 + h * 64 + d] = f2bf(val);
        }
    }
}

// ---------- K5: out = attn @ Wo^T + b_O + Q ----------
__global__ __launch_bounds__(256) void k_final(const short* __restrict__ A,
                                               const short* __restrict__ Bt,
                                               const float* __restrict__ bias,
                                               const float* __restrict__ Qres,
                                               float* __restrict__ out) {
    __shared__ short lA[2][4096];
    __shared__ short lB[2][4096];
    const int tid = threadIdx.x, w = tid >> 6, ln = tid & 63;
    const int wm = w >> 1, wn = w & 1, r16 = ln & 15, g = ln >> 4;
    const int tn = blockIdx.x * 128, tm = blockIdx.y * 128;
    const short* Ab = A + (size_t)tm * 1024;
    const short* Bb = Bt + (size_t)tn * 1024;

    f32x4 acc[4][4] = {};
    stage_tiles(Ab, Bb, &lA[0][0], &lB[0][0], w, ln);
    int buf = 0;
    for (int ks = 0; ks < 32; ks++) {
        __syncthreads();
        if (ks + 1 < 32)
            stage_tiles(Ab + (ks + 1) * 32, Bb + (ks + 1) * 32,
                        &lA[buf ^ 1][0], &lB[buf ^ 1][0], w, ln);
        frag8 af[4], bg[4];
#pragma unroll
        for (int mf = 0; mf < 4; mf++)
            af[mf] = *(const frag8*)&lA[buf][(wm * 64 + mf * 16 + r16) * 32 + g * 8];
#pragma unroll
        for (int nf = 0; nf < 4; nf++)
            bg[nf] = *(const frag8*)&lB[buf][(wn * 64 + nf * 16 + r16) * 32 + g * 8];
#pragma unroll
        for (int mf = 0; mf < 4; mf++)
#pragma unroll
            for (int nf = 0; nf < 4; nf++)
                acc[mf][nf] = MFMA16(af[mf], bg[nf], acc[mf][nf], 0, 0, 0);
        buf ^= 1;
    }
#pragma unroll
    for (int mf = 0; mf < 4; mf++)
#pragma unroll
        for (int nf = 0; nf < 4; nf++)
#pragma unroll
            for (int r = 0; r < 4; r++) {
                int m = tm + wm * 64 + mf * 16 + g * 4 + r;
                int n = tn + wn * 64 + nf * 16 + r16;
                float val = acc[mf][nf][r] + bias[n] + Qres[(size_t)m * 1024 + n];
                out[(size_t)m * 1024 + n] = val;
            }
}

// ---------- launch ----------
extern "C" void kernel_launch(void* const* d_in, const int* in_sizes, int n_in,
                              void* d_out, int out_size, void* d_ws, size_t ws_size,
                              hipStream_t stream) {
    (void)in_sizes; (void)n_in; (void)out_size; (void)ws_size;
    const float* Qf  = (const float*)d_in[0];
    const float* Kf  = (const float*)d_in[1];
    const float* Vf  = (const float*)d_in[2];
    const int*   msk = (const int*)d_in[3];
    const float* WQ  = (const float*)d_in[4];
    const float* bQ  = (const float*)d_in[5];
    const float* WK  = (const float*)d_in[6];
    const float* bK  = (const float*)d_in[7];
    const float* WV  = (const float*)d_in[8];
    const float* bV  = (const float*)d_in[9];
    const float* WO  = (const float*)d_in[10];
    const float* bO  = (const float*)d_in[11];
    float* out = (float*)d_out;

    char* p = (char*)d_ws;
    const size_t SZ_ACT = (size_t)4096 * 1024 * 2;  // 8 MB bf16
    const size_t SZ_W   = (size_t)1024 * 1024 * 2;  // 2 MB
    short* Qb  = (short*)p; p += SZ_ACT;
    short* Kb  = (short*)p; p += SZ_ACT;
    short* Vb  = (short*)p; p += SZ_ACT;
    short* Wqb = (short*)p; p += SZ_W;
    short* Wkb = (short*)p; p += SZ_W;
    short* Wvb = (short*)p; p += SZ_W;
    short* Wob = (short*)p; p += SZ_W;
    short* q_s = (short*)p; p += SZ_ACT;
    short* k_s = (short*)p; p += SZ_ACT;
    short* v_s = (short*)p; p += SZ_ACT;
    short* vhatT = Kb;  // dead after proj
    short* attn  = Qb;  // dead after proj

    // K0: fused converts
    k_cvt_all<<<4096, 256, 0, stream>>>(Qf, Kf, Vf, WQ, WK, WV, WO,
                                        Qb, Kb, Vb, Wqb, Wkb, Wvb, Wob);

    // K1: fused projections (z: 0=Q scaled, 1=K, 2=V)
    k_proj3<<<dim3(8, 32, 3), 256, 0, stream>>>(Qb, Kb, Vb, Wqb, Wkb, Wvb,
                                                bQ, bK, bV, q_s, k_s, v_s);

    // K2: column softmax denominators + fused v-scale/transpose
    k_stats<<<1024, 256, 0, stream>>>(k_s, q_s, msk, v_s, vhatT);

    // K4: attention apply
    k_apply<<<1024, 256, 0, stream>>>(q_s, k_s, vhatT, msk, attn);

    // K5: output projection + bias + residual
    k_final<<<dim3(8, 32), 256, 0, stream>>>(attn, Wob, bO, Qf, out);
}